// Round 7
// baseline (12966.670 us; speedup 1.0000x reference)
//
#include <hip/hip_runtime.h>
#include <stdint.h>

typedef unsigned short u16;
typedef unsigned int   u32;
typedef unsigned char  u8;
typedef signed char    s8;

#define B_    128
#define S_    1024
#define H_    1024
#define E_    256
#define EMB_  100
#define EMBP_ 128
#define V_    50000
#define NTOK_ (B_*S_)

typedef __attribute__((ext_vector_type(8))) short bf16x8;
typedef __attribute__((ext_vector_type(4))) float f32x4;
typedef __attribute__((ext_vector_type(4))) int   i32x4;

__device__ __forceinline__ u16 f2bf(float f){ u32 x=__float_as_uint(f); return (u16)((x + 0x7FFFu + ((x>>16)&1u))>>16); }
__device__ __forceinline__ float quantw(float w){ float r = rintf(w*16.f)*0.0625f; return fminf(fmaxf(r,-0.9375f),0.9375f); }

__device__ __forceinline__ void gll16(const void* g, void* l){
  __builtin_amdgcn_global_load_lds((const __attribute__((address_space(1))) void*)g,
                                   (__attribute__((address_space(3))) void*)l, 16, 0, 0);
}

// ---------------- merged, vectorized prep (x4 per thread; absorbs both memsets) ----------------

#define U0 1600000   // embhi  (V_*EMBP_/4)
#define U1 8192      // w1hi   (E_*EMBP_/4)
#define U2 65536     // qW2i   (H_*E_/4)
#define U3 256       // b2br2  (H_/4)
#define U4 32        // firstspk (B_/4)
#define UT (U0+U1+U2+U3+U4)

__global__ __launch_bounds__(256) void prep_all_k(const float* __restrict__ emb,
    const float* __restrict__ W1, const float* __restrict__ W2,
    const float* __restrict__ b2, const float* __restrict__ br2,
    u16* __restrict__ embhi, u16* __restrict__ w1hi, s8* __restrict__ qW2i,
    float* __restrict__ b2br2, int* __restrict__ firstspk)
{
  int u = blockIdx.x*256 + threadIdx.x;
  if (u < U0){
    int j = u*4, v = j >> 7, k = j & 127;
    f32x4 x = (f32x4)0.f;
    if (k < EMB_) x = *(const f32x4*)&emb[v*EMB_ + k];
    u32 w0 = (u32)f2bf(x[0]) | ((u32)f2bf(x[1]) << 16);
    u32 w1 = (u32)f2bf(x[2]) | ((u32)f2bf(x[3]) << 16);
    uint2 wv; wv.x = w0; wv.y = w1;
    *(uint2*)&embhi[j] = wv;
  } else if ((u -= U0) < U1){
    int j = u*4, n = j >> 7, k = j & 127;
    f32x4 x = (f32x4)0.f;
    if (k < EMB_) x = *(const f32x4*)&W1[n*EMB_ + k];
    u32 w0 = (u32)f2bf(x[0]) | ((u32)f2bf(x[1]) << 16);
    u32 w1 = (u32)f2bf(x[2]) | ((u32)f2bf(x[3]) << 16);
    uint2 wv; wv.x = w0; wv.y = w1;
    *(uint2*)&w1hi[j] = wv;
  } else if ((u -= U1) < U2){
    f32x4 x = *(const f32x4*)&W2[u*4];
    u32 pk = 0;
    #pragma unroll
    for (int i = 0; i < 4; ++i){
      float q = fminf(fmaxf(rintf(x[i]*16.f), -15.f), 15.f);
      pk |= ((u32)((int)q & 255)) << (i*8);
    }
    ((u32*)qW2i)[u] = pk;
  } else if ((u -= U2) < U3){
    f32x4 a = *(const f32x4*)&b2[u*4];
    f32x4 c = *(const f32x4*)&br2[u*4];
    *(f32x4*)&b2br2[u*4] = a + c;
  } else if ((u -= U3) < U4){
    ((int*)firstspk)[u] = 0x7F7F7F7F;
  }
}

// ---------------- GEMM1: xq = quant(relu(gather(emb) @ W1^T + b1)) as int8 (x16) ----------------
// M=64 x N=128, K=128 staged once. B frags direct from global (L2-resident). Epilogue
// bounces the u8 tile through LDS -> 2 coalesced dwordx4 stores/thread (was 32 byte-stores).

__global__ __launch_bounds__(256, 2) void gemm1_k(const int* __restrict__ inputs,
    const u16* __restrict__ embhi, const u16* __restrict__ w1hi,
    const float* __restrict__ b1, u8* __restrict__ xq)
{
  __shared__ __align__(16) char As[16384];   // A tile; reused as 8KB u8 bounce buffer
  const int tid = threadIdx.x;
  const int bx = blockIdx.x;                 // 4096 blocks
  const int n0 = ((bx >> 3) & 1) * 128;
  const int m0 = ((bx & 7)*256 + (bx >> 4)) * 64;
  const int l = tid & 63, wid = tid >> 6;
  const int wm = wid & 1, wn = wid >> 1;     // wave tile 32t x 64n
  const int l4 = l >> 4;

  // B fragments direct from global (issue first; waited at first MFMA use)
  bf16x8 bfv[4][4];
  #pragma unroll
  for (int kk = 0; kk < 4; ++kk)
    #pragma unroll
    for (int ni = 0; ni < 4; ++ni){
      int row = n0 + wn*64 + ni*16 + (l & 15);
      bfv[kk][ni] = *(const bf16x8*)((const char*)w1hi + (size_t)row*256 + kk*64 + l4*16);
    }

  // stage A (64 gathered emb rows, full K) async -> LDS
  #pragma unroll
  for (int i = 0; i < 4; ++i){
    int p = tid + i*256, r = p >> 4, g = p & 15;
    long ga = (long)inputs[m0 + r];
    gll16((const char*)embhi + ga*256 + ((g ^ (r & 15))*16), As + p*16);
  }
  __syncthreads();

  f32x4 acc[2][4];
  #pragma unroll
  for (int mi = 0; mi < 2; ++mi)
    #pragma unroll
    for (int ni = 0; ni < 4; ++ni)
      acc[mi][ni] = (f32x4)0.f;

  #pragma unroll
  for (int kk = 0; kk < 4; ++kk){
    bf16x8 af[2];
    #pragma unroll
    for (int mi = 0; mi < 2; ++mi){
      int rA = wm*32 + mi*16 + (l & 15);
      af[mi] = *(const bf16x8*)&As[rA*256 + (((kk*4 + l4) ^ (rA & 15))*16)];
    }
    __builtin_amdgcn_s_setprio(1);
    #pragma unroll
    for (int mi = 0; mi < 2; ++mi)
      #pragma unroll
      for (int ni = 0; ni < 4; ++ni)
        acc[mi][ni] = __builtin_amdgcn_mfma_f32_16x16x32_bf16(af[mi], bfv[kk][ni], acc[mi][ni], 0, 0, 0);
    __builtin_amdgcn_s_setprio(0);
  }

  __syncthreads();                            // all A reads done -> As reusable as bounce

  // quantize -> LDS bounce [64t][128e] u8
  #pragma unroll
  for (int mi = 0; mi < 2; ++mi){
    #pragma unroll
    for (int ni = 0; ni < 4; ++ni){
      int e = wn*64 + ni*16 + (l & 15);
      float bv = b1[n0 + e];
      #pragma unroll
      for (int j = 0; j < 4; ++j){
        int t = wm*32 + mi*16 + l4*4 + j;
        float v = fmaxf(acc[mi][ni][j] + bv, 0.f);
        int q = (int)rintf(v*16.f);
        q = (q > 15) ? 15 : q;
        As[t*128 + e] = (char)q;
      }
    }
  }
  __syncthreads();

  // coalesced write-out: 512 x 16B chunks
  #pragma unroll
  for (int q = 0; q < 2; ++q){
    int p = tid + q*256, t = p >> 3, e16 = (p & 7)*16;
    uint4 v = *(const uint4*)&As[t*128 + e16];
    *(uint4*)(xq + (size_t)(m0 + t)*E_ + n0 + e16) = v;
  }
}

// ---------------- GEMM2 + spike screen (no I materialization, no scan) ----------------
// Spike requires m > 0.5; with decay 0.2, m < max(I)/0.8, so: no I > 0.4 => no spike.
// Screen: running i32-max of MFMA accumulators (exact I), trip at 0.399 (1e-3 margin).
// B frags direct from global; A double-buffered 2x16KB; one barrier per subtile.

__global__ __launch_bounds__(256, 2) void gemm2_k(const s8* __restrict__ xq,
    const s8* __restrict__ qW2i, const float* __restrict__ b2br2, int* __restrict__ firstspike)
{
  __shared__ __align__(16) char LB[32768];   // A dbuf: 2 x (64t x 256k i8)
  const int tid = threadIdx.x;
  const int bx  = blockIdx.x;
  const int xcd = bx & 7, idx = bx >> 3;
  const int b   = xcd*16 + (idx >> 3);       // all 8 h-slices of a batch on one XCD
  const int n0  = (idx & 7) * 128;
  const int l = tid & 63, wid = tid >> 6;
  const int wm = wid >> 1, wn = wid & 1;     // wave tile 32t x 64h
  const int l4 = l >> 4;

  // B fragments + bias, direct from global (L2-resident)
  i32x4 bq[4][4];
  float be[4];
  #pragma unroll
  for (int ni = 0; ni < 4; ++ni){
    int row = n0 + wn*64 + ni*16 + (l & 15);
    #pragma unroll
    for (int ks = 0; ks < 4; ++ks)
      bq[ni][ks] = *(const i32x4*)(qW2i + (size_t)row*256 + ks*64 + l4*16);
    be[ni] = b2br2[row];
  }

  // stage A(0)
  const s8* Ab0 = xq + (size_t)b*S_*E_;
  #pragma unroll
  for (int i = 0; i < 4; ++i){
    int p = tid + i*256, r = p >> 4, g = p & 15;
    gll16(Ab0 + (size_t)r*256 + ((g ^ (r & 15))*16), LB + p*16);
  }
  __syncthreads();

  const int rA0 = wm*32 + (l & 15), rA1 = rA0 + 16;
  int rmax[4] = {(int)0x80000000, (int)0x80000000, (int)0x80000000, (int)0x80000000};

  for (int s = 0; s < 16; ++s){
    // prefetch next A tile into the other buffer (landed by end-of-iter barrier)
    if (s < 15){
      const s8* Ab = Ab0 + (size_t)(s + 1)*64*256;
      char* dst = LB + ((s + 1) & 1)*16384;
      #pragma unroll
      for (int i = 0; i < 4; ++i){
        int p = tid + i*256, r = p >> 4, g = p & 15;
        gll16(Ab + (size_t)r*256 + ((g ^ (r & 15))*16), dst + p*16);
      }
    }
    const char* cur = LB + (s & 1)*16384;
    i32x4 acc[2][4];
    #pragma unroll
    for (int mi = 0; mi < 2; ++mi)
      #pragma unroll
      for (int ni = 0; ni < 4; ++ni)
        acc[mi][ni] = (i32x4)0;

    __builtin_amdgcn_s_setprio(1);
    #pragma unroll
    for (int ks = 0; ks < 4; ++ks){
      i32x4 a0 = *(const i32x4*)&cur[rA0*256 + (((ks*4 + l4) ^ (rA0 & 15))*16)];
      i32x4 a1 = *(const i32x4*)&cur[rA1*256 + (((ks*4 + l4) ^ (rA1 & 15))*16)];
      #pragma unroll
      for (int ni = 0; ni < 4; ++ni){
        acc[0][ni] = __builtin_amdgcn_mfma_i32_16x16x64_i8(a0, bq[ni][ks], acc[0][ni], 0, 0, 0);
        acc[1][ni] = __builtin_amdgcn_mfma_i32_16x16x64_i8(a1, bq[ni][ks], acc[1][ni], 0, 0, 0);
      }
    }
    __builtin_amdgcn_s_setprio(0);

    // running exact-I max (integer domain)
    #pragma unroll
    for (int ni = 0; ni < 4; ++ni)
      #pragma unroll
      for (int mi = 0; mi < 2; ++mi)
        #pragma unroll
        for (int j = 0; j < 4; ++j)
          rmax[ni] = max(rmax[ni], acc[mi][ni][j]);

    __syncthreads();   // drains prefetch vmcnt; all reads of cur done
  }

  bool trip = false;
  #pragma unroll
  for (int ni = 0; ni < 4; ++ni)
    trip = trip || ((float)rmax[ni]*0.00390625f + be[ni] > 0.399f);
  if (trip) atomicMin(&firstspike[b], 0);
}

// ---------------- fused exact fallback + final projection ----------------
// Clean batch (no screen trip): sumspike == 0 -> out = b3. Tripped batch: replay the
// exact recurrence from xq (quantizing Wr2 on the fly), then project in-register.

__global__ __launch_bounds__(256) void fbfinal_k(const s8* __restrict__ xq, const s8* __restrict__ qW2i,
    const float* __restrict__ b2br2, const float* __restrict__ Wr2,
    const int* __restrict__ firstspike, const float* __restrict__ W3,
    const float* __restrict__ b3, float* __restrict__ out)
{
  const int b = blockIdx.x, tid = threadIdx.x;
  __shared__ int slist[H_];
  __shared__ int scount;
  __shared__ s8 xrow[E_];
  __shared__ float r0[4], r1[4];
  float ss[4] = {0,0,0,0};

  if (firstspike[b] < S_){
    float mem[4] = {0,0,0,0}, sp[4] = {0,0,0,0};
    for (int t = 0; t < S_; ++t){
      if (tid == 0) scount = 0;
      __syncthreads();
      #pragma unroll
      for (int j = 0; j < 4; ++j)
        if (sp[j] > 0.5f){ int k = atomicAdd(&scount, 1); slist[k] = tid + j*256; }
      if (tid < 64) ((int*)xrow)[tid] = ((const int*)(xq + (size_t)(b*S_ + t)*E_))[tid];
      __syncthreads();
      int sc = scount;
      #pragma unroll
      for (int j = 0; j < 4; ++j){
        int h = tid + j*256;
        const s8* wr = qW2i + (size_t)h*E_;
        int ia = 0;
        #pragma unroll 4
        for (int k = 0; k < E_; k += 4){
          ia += (int)xrow[k]*(int)wr[k] + (int)xrow[k+1]*(int)wr[k+1]
              + (int)xrow[k+2]*(int)wr[k+2] + (int)xrow[k+3]*(int)wr[k+3];
        }
        float Iv = (float)ia*(1.f/256.f) + b2br2[h];
        float rec = 0.f;
        for (int u = 0; u < sc; ++u) rec += quantw(Wr2[(size_t)h*H_ + slist[u]]);
        mem[j] = mem[j]*0.2f*(1.f - sp[j]) + Iv + rec;
      }
      #pragma unroll
      for (int j = 0; j < 4; ++j){ float ns = (mem[j] > 0.5f) ? 1.f : 0.f; sp[j] = ns; ss[j] += ns; }
      __syncthreads();
    }
  }

  float p0 = 0.f, p1 = 0.f;
  #pragma unroll
  for (int j = 0; j < 4; ++j){
    int h = tid + j*256;
    p0 += ss[j]*W3[h]; p1 += ss[j]*W3[H_ + h];
  }
  #pragma unroll
  for (int o = 32; o > 0; o >>= 1){ p0 += __shfl_down(p0, o, 64); p1 += __shfl_down(p1, o, 64); }
  if ((tid & 63) == 0){ r0[tid >> 6] = p0; r1[tid >> 6] = p1; }
  __syncthreads();
  if (tid == 0){
    out[b*2 + 0] = r0[0] + r0[1] + r0[2] + r0[3] + b3[0];
    out[b*2 + 1] = r1[0] + r1[1] + r1[2] + r1[3] + b3[1];
  }
}

// ---------------- host ----------------

extern "C" void kernel_launch(void* const* d_in, const int* in_sizes, int n_in,
                              void* d_out, int out_size, void* d_ws, size_t ws_size,
                              hipStream_t stream)
{
  (void)in_sizes; (void)n_in; (void)out_size; (void)ws_size;
  const int*   inputs = (const int*)  d_in[0];
  const float* emb    = (const float*)d_in[1];
  const float* W1     = (const float*)d_in[2];
  const float* b1     = (const float*)d_in[3];
  const float* W2     = (const float*)d_in[4];
  const float* b2     = (const float*)d_in[5];
  const float* Wr2    = (const float*)d_in[6];
  const float* br2    = (const float*)d_in[7];
  const float* W3     = (const float*)d_in[8];
  const float* b3     = (const float*)d_in[9];
  float* out = (float*)d_out;
  char* ws = (char*)d_ws;

  size_t off = 0;
  auto alloc = [&](size_t bytes)->char*{
    char* p = ws + off; off = (off + bytes + 255) & ~(size_t)255; return p;
  };
  u16*   embhi    = (u16*)  alloc((size_t)V_*EMBP_*2);   // 12.8 MB
  u16*   w1hi     = (u16*)  alloc((size_t)E_*EMBP_*2);
  s8*    qW2i     = (s8*)   alloc((size_t)H_*E_);
  float* b2br2    = (float*)alloc((size_t)H_*4);
  u8*    xq       = (u8*)   alloc((size_t)NTOK_*E_);     // 32 MB
  int*   firstspk = (int*)  alloc((size_t)B_*4);

  prep_all_k<<<(UT + 255)/256, 256, 0, stream>>>(emb, W1, W2, b2, br2,
                                                 embhi, w1hi, qW2i, b2br2, firstspk);
  gemm1_k<<<4096, 256, 0, stream>>>(inputs, embhi, w1hi, b1, xq);
  gemm2_k<<<1024, 256, 0, stream>>>((const s8*)xq, qW2i, b2br2, firstspk);
  fbfinal_k<<<B_, 256, 0, stream>>>((const s8*)xq, qW2i, b2br2, Wr2, firstspk, W3, b3, out);
}

// Round 8
// 156.969 us; speedup vs baseline: 82.6066x; 82.6066x over previous
//
#include <hip/hip_runtime.h>
#include <stdint.h>

typedef unsigned short u16;
typedef unsigned int   u32;
typedef unsigned char  u8;
typedef signed char    s8;

#define B_    128
#define S_    1024
#define H_    1024
#define E_    256
#define EMB_  100
#define EMBP_ 128
#define V_    50000
#define NTOK_ (B_*S_)

typedef __attribute__((ext_vector_type(8))) short bf16x8;
typedef __attribute__((ext_vector_type(4))) float f32x4;
typedef __attribute__((ext_vector_type(4))) int   i32x4;

__device__ __forceinline__ u16 f2bf(float f){ u32 x=__float_as_uint(f); return (u16)((x + 0x7FFFu + ((x>>16)&1u))>>16); }
__device__ __forceinline__ float quantw(float w){ float r = rintf(w*16.f)*0.0625f; return fminf(fmaxf(r,-0.9375f),0.9375f); }

__device__ __forceinline__ void gll16(const void* g, void* l){
  __builtin_amdgcn_global_load_lds((const __attribute__((address_space(1))) void*)g,
                                   (__attribute__((address_space(3))) void*)l, 16, 0, 0);
}

// ---------------- merged, vectorized prep (x4 per thread; absorbs both memsets) ----------------

#define U0 1600000   // embhi  (V_*EMBP_/4)
#define U1 8192      // w1hi   (E_*EMBP_/4)
#define U2 65536     // qW2i   (H_*E_/4)
#define U3 256       // b2br2  (H_/4)
#define U4 32        // firstspk (B_/4, int4 per thread)
#define UT (U0+U1+U2+U3+U4)

__global__ __launch_bounds__(256) void prep_all_k(const float* __restrict__ emb,
    const float* __restrict__ W1, const float* __restrict__ W2,
    const float* __restrict__ b2, const float* __restrict__ br2,
    u16* __restrict__ embhi, u16* __restrict__ w1hi, s8* __restrict__ qW2i,
    float* __restrict__ b2br2, int* __restrict__ firstspk)
{
  int u = blockIdx.x*256 + threadIdx.x;
  if (u < U0){
    int j = u*4, v = j >> 7, k = j & 127;
    f32x4 x = (f32x4)0.f;
    if (k < EMB_) x = *(const f32x4*)&emb[v*EMB_ + k];
    u32 w0 = (u32)f2bf(x[0]) | ((u32)f2bf(x[1]) << 16);
    u32 w1 = (u32)f2bf(x[2]) | ((u32)f2bf(x[3]) << 16);
    uint2 wv; wv.x = w0; wv.y = w1;
    *(uint2*)&embhi[j] = wv;
  } else if ((u -= U0) < U1){
    int j = u*4, n = j >> 7, k = j & 127;
    f32x4 x = (f32x4)0.f;
    if (k < EMB_) x = *(const f32x4*)&W1[n*EMB_ + k];
    u32 w0 = (u32)f2bf(x[0]) | ((u32)f2bf(x[1]) << 16);
    u32 w1 = (u32)f2bf(x[2]) | ((u32)f2bf(x[3]) << 16);
    uint2 wv; wv.x = w0; wv.y = w1;
    *(uint2*)&w1hi[j] = wv;
  } else if ((u -= U1) < U2){
    f32x4 x = *(const f32x4*)&W2[u*4];
    u32 pk = 0;
    #pragma unroll
    for (int i = 0; i < 4; ++i){
      float q = fminf(fmaxf(rintf(x[i]*16.f), -15.f), 15.f);
      pk |= ((u32)((int)q & 255)) << (i*8);
    }
    ((u32*)qW2i)[u] = pk;
  } else if ((u -= U2) < U3){
    f32x4 a = *(const f32x4*)&b2[u*4];
    f32x4 c = *(const f32x4*)&br2[u*4];
    *(f32x4*)&b2br2[u*4] = a + c;
  } else if ((u -= U3) < U4){
    int4 v; v.x = v.y = v.z = v.w = 0x7F7F7F7F;    // FIX r7: int4 per thread -> all 128 ints
    *(int4*)&firstspk[u*4] = v;
  }
}

// ---------------- GEMM1: xq = quant(relu(gather(emb) @ W1^T + b1)) as int8 (x16) ----------------
// M=64 x N=128, K=128 staged once. B frags direct from global (L2-resident). Epilogue
// bounces the u8 tile through LDS -> 2 coalesced dwordx4 stores/thread (was 32 byte-stores).

__global__ __launch_bounds__(256, 2) void gemm1_k(const int* __restrict__ inputs,
    const u16* __restrict__ embhi, const u16* __restrict__ w1hi,
    const float* __restrict__ b1, u8* __restrict__ xq)
{
  __shared__ __align__(16) char As[16384];   // A tile; reused as 8KB u8 bounce buffer
  const int tid = threadIdx.x;
  const int bx = blockIdx.x;                 // 4096 blocks
  const int n0 = ((bx >> 3) & 1) * 128;
  const int m0 = ((bx & 7)*256 + (bx >> 4)) * 64;
  const int l = tid & 63, wid = tid >> 6;
  const int wm = wid & 1, wn = wid >> 1;     // wave tile 32t x 64n
  const int l4 = l >> 4;

  // B fragments direct from global (issue first; waited at first MFMA use)
  bf16x8 bfv[4][4];
  #pragma unroll
  for (int kk = 0; kk < 4; ++kk)
    #pragma unroll
    for (int ni = 0; ni < 4; ++ni){
      int row = n0 + wn*64 + ni*16 + (l & 15);
      bfv[kk][ni] = *(const bf16x8*)((const char*)w1hi + (size_t)row*256 + kk*64 + l4*16);
    }

  // stage A (64 gathered emb rows, full K) async -> LDS
  #pragma unroll
  for (int i = 0; i < 4; ++i){
    int p = tid + i*256, r = p >> 4, g = p & 15;
    long ga = (long)inputs[m0 + r];
    gll16((const char*)embhi + ga*256 + ((g ^ (r & 15))*16), As + p*16);
  }
  __syncthreads();

  f32x4 acc[2][4];
  #pragma unroll
  for (int mi = 0; mi < 2; ++mi)
    #pragma unroll
    for (int ni = 0; ni < 4; ++ni)
      acc[mi][ni] = (f32x4)0.f;

  #pragma unroll
  for (int kk = 0; kk < 4; ++kk){
    bf16x8 af[2];
    #pragma unroll
    for (int mi = 0; mi < 2; ++mi){
      int rA = wm*32 + mi*16 + (l & 15);
      af[mi] = *(const bf16x8*)&As[rA*256 + (((kk*4 + l4) ^ (rA & 15))*16)];
    }
    __builtin_amdgcn_s_setprio(1);
    #pragma unroll
    for (int mi = 0; mi < 2; ++mi)
      #pragma unroll
      for (int ni = 0; ni < 4; ++ni)
        acc[mi][ni] = __builtin_amdgcn_mfma_f32_16x16x32_bf16(af[mi], bfv[kk][ni], acc[mi][ni], 0, 0, 0);
    __builtin_amdgcn_s_setprio(0);
  }

  __syncthreads();                            // all A reads done -> As reusable as bounce

  // quantize -> LDS bounce [64t][128e] u8
  #pragma unroll
  for (int mi = 0; mi < 2; ++mi){
    #pragma unroll
    for (int ni = 0; ni < 4; ++ni){
      int e = wn*64 + ni*16 + (l & 15);
      float bv = b1[n0 + e];
      #pragma unroll
      for (int j = 0; j < 4; ++j){
        int t = wm*32 + mi*16 + l4*4 + j;
        float v = fmaxf(acc[mi][ni][j] + bv, 0.f);
        int q = (int)rintf(v*16.f);
        q = (q > 15) ? 15 : q;
        As[t*128 + e] = (char)q;
      }
    }
  }
  __syncthreads();

  // coalesced write-out: 512 x 16B chunks
  #pragma unroll
  for (int q = 0; q < 2; ++q){
    int p = tid + q*256, t = p >> 3, e16 = (p & 7)*16;
    uint4 v = *(const uint4*)&As[t*128 + e16];
    *(uint4*)(xq + (size_t)(m0 + t)*E_ + n0 + e16) = v;
  }
}

// ---------------- GEMM2 + spike screen (no I materialization, no scan) ----------------
// Spike requires m > 0.5; with decay 0.2, m < max(I)/0.8, so: no I > 0.4 => no spike.
// Screen: running i32-max of MFMA accumulators (exact I), trip at 0.399 (1e-3 margin).
// B frags direct from global; A double-buffered 2x16KB; one barrier per subtile.

__global__ __launch_bounds__(256, 2) void gemm2_k(const s8* __restrict__ xq,
    const s8* __restrict__ qW2i, const float* __restrict__ b2br2, int* __restrict__ firstspike)
{
  __shared__ __align__(16) char LB[32768];   // A dbuf: 2 x (64t x 256k i8)
  const int tid = threadIdx.x;
  const int bx  = blockIdx.x;
  const int xcd = bx & 7, idx = bx >> 3;
  const int b   = xcd*16 + (idx >> 3);       // all 8 h-slices of a batch on one XCD
  const int n0  = (idx & 7) * 128;
  const int l = tid & 63, wid = tid >> 6;
  const int wm = wid >> 1, wn = wid & 1;     // wave tile 32t x 64h
  const int l4 = l >> 4;

  // B fragments + bias, direct from global (L2-resident)
  i32x4 bq[4][4];
  float be[4];
  #pragma unroll
  for (int ni = 0; ni < 4; ++ni){
    int row = n0 + wn*64 + ni*16 + (l & 15);
    #pragma unroll
    for (int ks = 0; ks < 4; ++ks)
      bq[ni][ks] = *(const i32x4*)(qW2i + (size_t)row*256 + ks*64 + l4*16);
    be[ni] = b2br2[row];
  }

  // stage A(0)
  const s8* Ab0 = xq + (size_t)b*S_*E_;
  #pragma unroll
  for (int i = 0; i < 4; ++i){
    int p = tid + i*256, r = p >> 4, g = p & 15;
    gll16(Ab0 + (size_t)r*256 + ((g ^ (r & 15))*16), LB + p*16);
  }
  __syncthreads();

  const int rA0 = wm*32 + (l & 15), rA1 = rA0 + 16;
  int rmax[4] = {(int)0x80000000, (int)0x80000000, (int)0x80000000, (int)0x80000000};

  for (int s = 0; s < 16; ++s){
    // prefetch next A tile into the other buffer (landed by end-of-iter barrier)
    if (s < 15){
      const s8* Ab = Ab0 + (size_t)(s + 1)*64*256;
      char* dst = LB + ((s + 1) & 1)*16384;
      #pragma unroll
      for (int i = 0; i < 4; ++i){
        int p = tid + i*256, r = p >> 4, g = p & 15;
        gll16(Ab + (size_t)r*256 + ((g ^ (r & 15))*16), dst + p*16);
      }
    }
    const char* cur = LB + (s & 1)*16384;
    i32x4 acc[2][4];
    #pragma unroll
    for (int mi = 0; mi < 2; ++mi)
      #pragma unroll
      for (int ni = 0; ni < 4; ++ni)
        acc[mi][ni] = (i32x4)0;

    __builtin_amdgcn_s_setprio(1);
    #pragma unroll
    for (int ks = 0; ks < 4; ++ks){
      i32x4 a0 = *(const i32x4*)&cur[rA0*256 + (((ks*4 + l4) ^ (rA0 & 15))*16)];
      i32x4 a1 = *(const i32x4*)&cur[rA1*256 + (((ks*4 + l4) ^ (rA1 & 15))*16)];
      #pragma unroll
      for (int ni = 0; ni < 4; ++ni){
        acc[0][ni] = __builtin_amdgcn_mfma_i32_16x16x64_i8(a0, bq[ni][ks], acc[0][ni], 0, 0, 0);
        acc[1][ni] = __builtin_amdgcn_mfma_i32_16x16x64_i8(a1, bq[ni][ks], acc[1][ni], 0, 0, 0);
      }
    }
    __builtin_amdgcn_s_setprio(0);

    // running exact-I max (integer domain)
    #pragma unroll
    for (int ni = 0; ni < 4; ++ni)
      #pragma unroll
      for (int mi = 0; mi < 2; ++mi)
        #pragma unroll
        for (int j = 0; j < 4; ++j)
          rmax[ni] = max(rmax[ni], acc[mi][ni][j]);

    __syncthreads();   // drains prefetch vmcnt; all reads of cur done
  }

  bool trip = false;
  #pragma unroll
  for (int ni = 0; ni < 4; ++ni)
    trip = trip || ((float)rmax[ni]*0.00390625f + be[ni] > 0.399f);
  if (trip) atomicMin(&firstspike[b], 0);
}

// ---------------- fused exact fallback + final projection ----------------
// Clean batch (no screen trip): sumspike == 0 -> out = b3. Tripped batch: replay the
// exact recurrence from xq (quantizing Wr2 on the fly), then project in-register.

__global__ __launch_bounds__(256) void fbfinal_k(const s8* __restrict__ xq, const s8* __restrict__ qW2i,
    const float* __restrict__ b2br2, const float* __restrict__ Wr2,
    const int* __restrict__ firstspike, const float* __restrict__ W3,
    const float* __restrict__ b3, float* __restrict__ out)
{
  const int b = blockIdx.x, tid = threadIdx.x;
  __shared__ int slist[H_];
  __shared__ int scount;
  __shared__ s8 xrow[E_];
  __shared__ float r0[4], r1[4];
  float ss[4] = {0,0,0,0};

  if (firstspike[b] < S_){
    float mem[4] = {0,0,0,0}, sp[4] = {0,0,0,0};
    for (int t = 0; t < S_; ++t){
      if (tid == 0) scount = 0;
      __syncthreads();
      #pragma unroll
      for (int j = 0; j < 4; ++j)
        if (sp[j] > 0.5f){ int k = atomicAdd(&scount, 1); slist[k] = tid + j*256; }
      if (tid < 64) ((int*)xrow)[tid] = ((const int*)(xq + (size_t)(b*S_ + t)*E_))[tid];
      __syncthreads();
      int sc = scount;
      #pragma unroll
      for (int j = 0; j < 4; ++j){
        int h = tid + j*256;
        const s8* wr = qW2i + (size_t)h*E_;
        int ia = 0;
        #pragma unroll 4
        for (int k = 0; k < E_; k += 4){
          ia += (int)xrow[k]*(int)wr[k] + (int)xrow[k+1]*(int)wr[k+1]
              + (int)xrow[k+2]*(int)wr[k+2] + (int)xrow[k+3]*(int)wr[k+3];
        }
        float Iv = (float)ia*(1.f/256.f) + b2br2[h];
        float rec = 0.f;
        for (int u = 0; u < sc; ++u) rec += quantw(Wr2[(size_t)h*H_ + slist[u]]);
        mem[j] = mem[j]*0.2f*(1.f - sp[j]) + Iv + rec;
      }
      #pragma unroll
      for (int j = 0; j < 4; ++j){ float ns = (mem[j] > 0.5f) ? 1.f : 0.f; sp[j] = ns; ss[j] += ns; }
      __syncthreads();
    }
  }

  float p0 = 0.f, p1 = 0.f;
  #pragma unroll
  for (int j = 0; j < 4; ++j){
    int h = tid + j*256;
    p0 += ss[j]*W3[h]; p1 += ss[j]*W3[H_ + h];
  }
  #pragma unroll
  for (int o = 32; o > 0; o >>= 1){ p0 += __shfl_down(p0, o, 64); p1 += __shfl_down(p1, o, 64); }
  if ((tid & 63) == 0){ r0[tid >> 6] = p0; r1[tid >> 6] = p1; }
  __syncthreads();
  if (tid == 0){
    out[b*2 + 0] = r0[0] + r0[1] + r0[2] + r0[3] + b3[0];
    out[b*2 + 1] = r1[0] + r1[1] + r1[2] + r1[3] + b3[1];
  }
}

// ---------------- host ----------------

extern "C" void kernel_launch(void* const* d_in, const int* in_sizes, int n_in,
                              void* d_out, int out_size, void* d_ws, size_t ws_size,
                              hipStream_t stream)
{
  (void)in_sizes; (void)n_in; (void)out_size; (void)ws_size;
  const int*   inputs = (const int*)  d_in[0];
  const float* emb    = (const float*)d_in[1];
  const float* W1     = (const float*)d_in[2];
  const float* b1     = (const float*)d_in[3];
  const float* W2     = (const float*)d_in[4];
  const float* b2     = (const float*)d_in[5];
  const float* Wr2    = (const float*)d_in[6];
  const float* br2    = (const float*)d_in[7];
  const float* W3     = (const float*)d_in[8];
  const float* b3     = (const float*)d_in[9];
  float* out = (float*)d_out;
  char* ws = (char*)d_ws;

  size_t off = 0;
  auto alloc = [&](size_t bytes)->char*{
    char* p = ws + off; off = (off + bytes + 255) & ~(size_t)255; return p;
  };
  u16*   embhi    = (u16*)  alloc((size_t)V_*EMBP_*2);   // 12.8 MB
  u16*   w1hi     = (u16*)  alloc((size_t)E_*EMBP_*2);
  s8*    qW2i     = (s8*)   alloc((size_t)H_*E_);
  float* b2br2    = (float*)alloc((size_t)H_*4);
  u8*    xq       = (u8*)   alloc((size_t)NTOK_*E_);     // 32 MB
  int*   firstspk = (int*)  alloc((size_t)B_*4);

  prep_all_k<<<(UT + 255)/256, 256, 0, stream>>>(emb, W1, W2, b2, br2,
                                                 embhi, w1hi, qW2i, b2br2, firstspk);
  gemm1_k<<<4096, 256, 0, stream>>>(inputs, embhi, w1hi, b1, xq);
  gemm2_k<<<1024, 256, 0, stream>>>((const s8*)xq, qW2i, b2br2, firstspk);
  fbfinal_k<<<B_, 256, 0, stream>>>((const s8*)xq, qW2i, b2br2, Wr2, firstspk, W3, b3, out);
}

// Round 10
// 156.499 us; speedup vs baseline: 82.8544x; 1.0030x over previous
//
#include <hip/hip_runtime.h>
#include <stdint.h>

typedef unsigned short u16;
typedef unsigned int   u32;
typedef unsigned char  u8;
typedef signed char    s8;

#define B_    128
#define S_    1024
#define H_    1024
#define E_    256
#define EMB_  100
#define EMBP_ 128
#define V_    50000
#define NTOK_ (B_*S_)

typedef __attribute__((ext_vector_type(8))) short bf16x8;
typedef __attribute__((ext_vector_type(4))) float f32x4;
typedef __attribute__((ext_vector_type(4))) int   i32x4;

__device__ __forceinline__ u16 f2bf(float f){ u32 x=__float_as_uint(f); return (u16)((x + 0x7FFFu + ((x>>16)&1u))>>16); }
__device__ __forceinline__ float quantw(float w){ float r = rintf(w*16.f)*0.0625f; return fminf(fmaxf(r,-0.9375f),0.9375f); }

__device__ __forceinline__ void gll16(const void* g, void* l){
  __builtin_amdgcn_global_load_lds((const __attribute__((address_space(1))) void*)g,
                                   (__attribute__((address_space(3))) void*)l, 16, 0, 0);
}

// ---------------- prep: emb/W1 bf16 conversion only (consumed by gemm1) ----------------

#define U0 1600000   // embhi  (V_*EMBP_/4)
#define U1 8192      // w1hi   (E_*EMBP_/4)
#define UTA (U0+U1)
// moved into gemm1's grid tail:
#define U2 65536     // qW2i   (H_*E_/4)
#define U3 256       // b2br2  (H_/4)
#define U4 32        // firstspk (B_/4, int4 per thread)
#define GX1 4096     // gemm1 compute blocks
#define GXE 258      // extra prep blocks appended to gemm1 grid

__global__ __launch_bounds__(256) void prep_all_k(const float* __restrict__ emb,
    const float* __restrict__ W1, u16* __restrict__ embhi, u16* __restrict__ w1hi)
{
  int u = blockIdx.x*256 + threadIdx.x;
  if (u < U0){
    int j = u*4, v = j >> 7, k = j & 127;
    f32x4 x = (f32x4)0.f;
    if (k < EMB_) x = *(const f32x4*)&emb[v*EMB_ + k];
    u32 w0 = (u32)f2bf(x[0]) | ((u32)f2bf(x[1]) << 16);
    u32 w1 = (u32)f2bf(x[2]) | ((u32)f2bf(x[3]) << 16);
    uint2 wv; wv.x = w0; wv.y = w1;
    *(uint2*)&embhi[j] = wv;
  } else if ((u -= U0) < U1){
    int j = u*4, n = j >> 7, k = j & 127;
    f32x4 x = (f32x4)0.f;
    if (k < EMB_) x = *(const f32x4*)&W1[n*EMB_ + k];
    u32 w0 = (u32)f2bf(x[0]) | ((u32)f2bf(x[1]) << 16);
    u32 w1 = (u32)f2bf(x[2]) | ((u32)f2bf(x[3]) << 16);
    uint2 wv; wv.x = w0; wv.y = w1;
    *(uint2*)&w1hi[j] = wv;
  }
}

// ---------------- GEMM1: xq = quant(relu(gather(emb) @ W1^T + b1)) as int8 (x16) ----------------
// M=64 x N=128, K=128 staged once. B frags direct from global (L2-resident). Epilogue
// bounces the u8 tile through LDS -> 2 coalesced dwordx4 stores/thread. Grid tail
// (blocks >= GX1) runs the W2/b2br2/firstspk prep (ready before gemm2 by stream order).

__global__ __launch_bounds__(256, 3) void gemm1_k(const int* __restrict__ inputs,
    const u16* __restrict__ embhi, const u16* __restrict__ w1hi,
    const float* __restrict__ b1, u8* __restrict__ xq,
    const float* __restrict__ W2, const float* __restrict__ b2, const float* __restrict__ br2,
    s8* __restrict__ qW2i, float* __restrict__ b2br2, int* __restrict__ firstspk)
{
  __shared__ __align__(16) char As[16384];   // A tile; reused as 8KB u8 bounce buffer
  const int tid = threadIdx.x;
  const int bx = blockIdx.x;

  if (bx >= GX1){                            // prep tail
    int u = (bx - GX1)*256 + tid;
    if (u < U2){
      f32x4 x = *(const f32x4*)&W2[u*4];
      u32 pk = 0;
      #pragma unroll
      for (int i = 0; i < 4; ++i){
        float q = fminf(fmaxf(rintf(x[i]*16.f), -15.f), 15.f);
        pk |= ((u32)((int)q & 255)) << (i*8);
      }
      ((u32*)qW2i)[u] = pk;
    } else if ((u -= U2) < U3){
      f32x4 a = *(const f32x4*)&b2[u*4];
      f32x4 c = *(const f32x4*)&br2[u*4];
      *(f32x4*)&b2br2[u*4] = a + c;
    } else if ((u -= U3) < U4){
      int4 v; v.x = v.y = v.z = v.w = 0x7F7F7F7F;
      *(int4*)&firstspk[u*4] = v;
    }
    return;
  }

  const int n0 = ((bx >> 3) & 1) * 128;
  const int m0 = ((bx & 7)*256 + (bx >> 4)) * 64;
  const int l = tid & 63, wid = tid >> 6;
  const int wm = wid & 1, wn = wid >> 1;     // wave tile 32t x 64n
  const int l4 = l >> 4;

  // B fragments direct from global (issue first; waited at first MFMA use)
  bf16x8 bfv[4][4];
  #pragma unroll
  for (int kk = 0; kk < 4; ++kk)
    #pragma unroll
    for (int ni = 0; ni < 4; ++ni){
      int row = n0 + wn*64 + ni*16 + (l & 15);
      bfv[kk][ni] = *(const bf16x8*)((const char*)w1hi + (size_t)row*256 + kk*64 + l4*16);
    }

  // stage A (64 gathered emb rows, full K) async -> LDS
  #pragma unroll
  for (int i = 0; i < 4; ++i){
    int p = tid + i*256, r = p >> 4, g = p & 15;
    long ga = (long)inputs[m0 + r];
    gll16((const char*)embhi + ga*256 + ((g ^ (r & 15))*16), As + p*16);
  }
  __syncthreads();

  f32x4 acc[2][4];
  #pragma unroll
  for (int mi = 0; mi < 2; ++mi)
    #pragma unroll
    for (int ni = 0; ni < 4; ++ni)
      acc[mi][ni] = (f32x4)0.f;

  #pragma unroll
  for (int kk = 0; kk < 4; ++kk){
    bf16x8 af[2];
    #pragma unroll
    for (int mi = 0; mi < 2; ++mi){
      int rA = wm*32 + mi*16 + (l & 15);
      af[mi] = *(const bf16x8*)&As[rA*256 + (((kk*4 + l4) ^ (rA & 15))*16)];
    }
    __builtin_amdgcn_s_setprio(1);
    #pragma unroll
    for (int mi = 0; mi < 2; ++mi)
      #pragma unroll
      for (int ni = 0; ni < 4; ++ni)
        acc[mi][ni] = __builtin_amdgcn_mfma_f32_16x16x32_bf16(af[mi], bfv[kk][ni], acc[mi][ni], 0, 0, 0);
    __builtin_amdgcn_s_setprio(0);
  }

  __syncthreads();                            // all A reads done -> As reusable as bounce

  // quantize -> LDS bounce [64t][128e] u8
  #pragma unroll
  for (int mi = 0; mi < 2; ++mi){
    #pragma unroll
    for (int ni = 0; ni < 4; ++ni){
      int e = wn*64 + ni*16 + (l & 15);
      float bv = b1[n0 + e];
      #pragma unroll
      for (int j = 0; j < 4; ++j){
        int t = wm*32 + mi*16 + l4*4 + j;
        float v = fmaxf(acc[mi][ni][j] + bv, 0.f);
        int q = (int)rintf(v*16.f);
        q = (q > 15) ? 15 : q;
        As[t*128 + e] = (char)q;
      }
    }
  }
  __syncthreads();

  // coalesced write-out: 512 x 16B chunks
  #pragma unroll
  for (int q = 0; q < 2; ++q){
    int p = tid + q*256, t = p >> 3, e16 = (p & 7)*16;
    uint4 v = *(const uint4*)&As[t*128 + e16];
    *(uint4*)(xq + (size_t)(m0 + t)*E_ + n0 + e16) = v;
  }
}

// ---------------- GEMM2 + spike screen (no I materialization, no scan) ----------------
// Spike requires m > 0.5; with decay 0.2, m < max(I)/0.8, so: no I > 0.4 => no spike.
// Screen: running i32-max of MFMA accumulators (exact I), trip at 0.399 (1e-3 margin).
// B frags direct from global; A double-buffered 2x16KB; one barrier per subtile.

__global__ __launch_bounds__(256, 3) void gemm2_k(const s8* __restrict__ xq,
    const s8* __restrict__ qW2i, const float* __restrict__ b2br2, int* __restrict__ firstspike)
{
  __shared__ __align__(16) char LB[32768];   // A dbuf: 2 x (64t x 256k i8)
  const int tid = threadIdx.x;
  const int bx  = blockIdx.x;
  const int xcd = bx & 7, idx = bx >> 3;
  const int b   = xcd*16 + (idx >> 3);       // all 8 h-slices of a batch on one XCD
  const int n0  = (idx & 7) * 128;
  const int l = tid & 63, wid = tid >> 6;
  const int wm = wid >> 1, wn = wid & 1;     // wave tile 32t x 64h
  const int l4 = l >> 4;

  // B fragments + bias, direct from global (L2-resident)
  i32x4 bq[4][4];
  float be[4];
  #pragma unroll
  for (int ni = 0; ni < 4; ++ni){
    int row = n0 + wn*64 + ni*16 + (l & 15);
    #pragma unroll
    for (int ks = 0; ks < 4; ++ks)
      bq[ni][ks] = *(const i32x4*)(qW2i + (size_t)row*256 + ks*64 + l4*16);
    be[ni] = b2br2[row];
  }

  // stage A(0)
  const s8* Ab0 = xq + (size_t)b*S_*E_;
  #pragma unroll
  for (int i = 0; i < 4; ++i){
    int p = tid + i*256, r = p >> 4, g = p & 15;
    gll16(Ab0 + (size_t)r*256 + ((g ^ (r & 15))*16), LB + p*16);
  }
  __syncthreads();

  const int rA0 = wm*32 + (l & 15), rA1 = rA0 + 16;
  int rmax[4] = {(int)0x80000000, (int)0x80000000, (int)0x80000000, (int)0x80000000};

  for (int s = 0; s < 16; ++s){
    // prefetch next A tile into the other buffer (landed by end-of-iter barrier)
    if (s < 15){
      const s8* Ab = Ab0 + (size_t)(s + 1)*64*256;
      char* dst = LB + ((s + 1) & 1)*16384;
      #pragma unroll
      for (int i = 0; i < 4; ++i){
        int p = tid + i*256, r = p >> 4, g = p & 15;
        gll16(Ab + (size_t)r*256 + ((g ^ (r & 15))*16), dst + p*16);
      }
    }
    const char* cur = LB + (s & 1)*16384;
    i32x4 acc[2][4];
    #pragma unroll
    for (int mi = 0; mi < 2; ++mi)
      #pragma unroll
      for (int ni = 0; ni < 4; ++ni)
        acc[mi][ni] = (i32x4)0;

    __builtin_amdgcn_s_setprio(1);
    #pragma unroll
    for (int ks = 0; ks < 4; ++ks){
      i32x4 a0 = *(const i32x4*)&cur[rA0*256 + (((ks*4 + l4) ^ (rA0 & 15))*16)];
      i32x4 a1 = *(const i32x4*)&cur[rA1*256 + (((ks*4 + l4) ^ (rA1 & 15))*16)];
      #pragma unroll
      for (int ni = 0; ni < 4; ++ni){
        acc[0][ni] = __builtin_amdgcn_mfma_i32_16x16x64_i8(a0, bq[ni][ks], acc[0][ni], 0, 0, 0);
        acc[1][ni] = __builtin_amdgcn_mfma_i32_16x16x64_i8(a1, bq[ni][ks], acc[1][ni], 0, 0, 0);
      }
    }
    __builtin_amdgcn_s_setprio(0);

    // running exact-I max (integer domain)
    #pragma unroll
    for (int ni = 0; ni < 4; ++ni)
      #pragma unroll
      for (int mi = 0; mi < 2; ++mi)
        #pragma unroll
        for (int j = 0; j < 4; ++j)
          rmax[ni] = max(rmax[ni], acc[mi][ni][j]);

    __syncthreads();   // drains prefetch vmcnt; all reads of cur done
  }

  bool trip = false;
  #pragma unroll
  for (int ni = 0; ni < 4; ++ni)
    trip = trip || ((float)rmax[ni]*0.00390625f + be[ni] > 0.399f);
  if (trip) atomicMin(&firstspike[b], 0);
}

// ---------------- fused exact fallback + final projection ----------------
// Clean batch (no screen trip): sumspike == 0 -> out = b3. Tripped batch: replay the
// exact recurrence from xq (quantizing Wr2 on the fly), then project in-register.

__global__ __launch_bounds__(256) void fbfinal_k(const s8* __restrict__ xq, const s8* __restrict__ qW2i,
    const float* __restrict__ b2br2, const float* __restrict__ Wr2,
    const int* __restrict__ firstspike, const float* __restrict__ W3,
    const float* __restrict__ b3, float* __restrict__ out)
{
  const int b = blockIdx.x, tid = threadIdx.x;
  __shared__ int slist[H_];
  __shared__ int scount;
  __shared__ s8 xrow[E_];
  __shared__ float r0[4], r1[4];
  float ss[4] = {0,0,0,0};

  if (firstspike[b] < S_){
    float mem[4] = {0,0,0,0}, sp[4] = {0,0,0,0};
    for (int t = 0; t < S_; ++t){
      if (tid == 0) scount = 0;
      __syncthreads();
      #pragma unroll
      for (int j = 0; j < 4; ++j)
        if (sp[j] > 0.5f){ int k = atomicAdd(&scount, 1); slist[k] = tid + j*256; }
      if (tid < 64) ((int*)xrow)[tid] = ((const int*)(xq + (size_t)(b*S_ + t)*E_))[tid];
      __syncthreads();
      int sc = scount;
      #pragma unroll
      for (int j = 0; j < 4; ++j){
        int h = tid + j*256;
        const s8* wr = qW2i + (size_t)h*E_;
        int ia = 0;
        #pragma unroll 4
        for (int k = 0; k < E_; k += 4){
          ia += (int)xrow[k]*(int)wr[k] + (int)xrow[k+1]*(int)wr[k+1]
              + (int)xrow[k+2]*(int)wr[k+2] + (int)xrow[k+3]*(int)wr[k+3];
        }
        float Iv = (float)ia*(1.f/256.f) + b2br2[h];
        float rec = 0.f;
        for (int u = 0; u < sc; ++u) rec += quantw(Wr2[(size_t)h*H_ + slist[u]]);
        mem[j] = mem[j]*0.2f*(1.f - sp[j]) + Iv + rec;
      }
      #pragma unroll
      for (int j = 0; j < 4; ++j){ float ns = (mem[j] > 0.5f) ? 1.f : 0.f; sp[j] = ns; ss[j] += ns; }
      __syncthreads();
    }
  }

  float p0 = 0.f, p1 = 0.f;
  #pragma unroll
  for (int j = 0; j < 4; ++j){
    int h = tid + j*256;
    p0 += ss[j]*W3[h]; p1 += ss[j]*W3[H_ + h];
  }
  #pragma unroll
  for (int o = 32; o > 0; o >>= 1){ p0 += __shfl_down(p0, o, 64); p1 += __shfl_down(p1, o, 64); }
  if ((tid & 63) == 0){ r0[tid >> 6] = p0; r1[tid >> 6] = p1; }
  __syncthreads();
  if (tid == 0){
    out[b*2 + 0] = r0[0] + r0[1] + r0[2] + r0[3] + b3[0];
    out[b*2 + 1] = r1[0] + r1[1] + r1[2] + r1[3] + b3[1];
  }
}

// ---------------- host ----------------

extern "C" void kernel_launch(void* const* d_in, const int* in_sizes, int n_in,
                              void* d_out, int out_size, void* d_ws, size_t ws_size,
                              hipStream_t stream)
{
  (void)in_sizes; (void)n_in; (void)out_size; (void)ws_size;
  const int*   inputs = (const int*)  d_in[0];
  const float* emb    = (const float*)d_in[1];
  const float* W1     = (const float*)d_in[2];
  const float* b1     = (const float*)d_in[3];
  const float* W2     = (const float*)d_in[4];
  const float* b2     = (const float*)d_in[5];
  const float* Wr2    = (const float*)d_in[6];
  const float* br2    = (const float*)d_in[7];
  const float* W3     = (const float*)d_in[8];
  const float* b3     = (const float*)d_in[9];
  float* out = (float*)d_out;
  char* ws = (char*)d_ws;

  size_t off = 0;
  auto alloc = [&](size_t bytes)->char*{
    char* p = ws + off; off = (off + bytes + 255) & ~(size_t)255; return p;
  };
  u16*   embhi    = (u16*)  alloc((size_t)V_*EMBP_*2);   // 12.8 MB
  u16*   w1hi     = (u16*)  alloc((size_t)E_*EMBP_*2);
  s8*    qW2i     = (s8*)   alloc((size_t)H_*E_);
  float* b2br2    = (float*)alloc((size_t)H_*4);
  u8*    xq       = (u8*)   alloc((size_t)NTOK_*E_);     // 32 MB
  int*   firstspk = (int*)  alloc((size_t)B_*4);

  prep_all_k<<<(UTA + 255)/256, 256, 0, stream>>>(emb, W1, embhi, w1hi);
  gemm1_k<<<GX1 + GXE, 256, 0, stream>>>(inputs, embhi, w1hi, b1, xq,
                                         W2, b2, br2, qW2i, b2br2, firstspk);
  gemm2_k<<<1024, 256, 0, stream>>>((const s8*)xq, qW2i, b2br2, firstspk);
  fbfinal_k<<<B_, 256, 0, stream>>>((const s8*)xq, qW2i, b2br2, Wr2, firstspk, W3, b3, out);
}